// Round 1
// baseline (148.638 us; speedup 1.0000x reference)
//
#include <hip/hip_runtime.h>
#include <math.h>

#define TPB 256

// ---------------------------------------------------------------------------
// Kernel 1: per-gaussian preprocessing.
// params layout per gaussian (stride 12 floats = 3 float4):
//   [0] mx  [1] my  [2] ia  [3] ibc  [4] id  [5] alpha
//   [6] r   [7] g   [8] b   [9..11] pad
// ---------------------------------------------------------------------------
__global__ void gs_preprocess(const float* __restrict__ pose,
                              const float* __restrict__ positions,
                              const float* __restrict__ scales,
                              const float* __restrict__ rotations,
                              const float* __restrict__ opacity,
                              const float* __restrict__ features,
                              float* __restrict__ depths,
                              float* __restrict__ params,
                              int N, int B)
{
    int idx = blockIdx.x * blockDim.x + threadIdx.x;
    if (idx >= B * N) return;
    int b = idx / N;
    int n = idx - b * N;
    const float* P = pose + b * 16;

    float x = positions[n * 3 + 0];
    float y = positions[n * 3 + 1];
    float z = positions[n * 3 + 2];

    // cam = pose @ [x,y,z,1]
    float cam0 = P[0] * x + P[1] * y + P[2]  * z + P[3];
    float cam1 = P[4] * x + P[5] * y + P[6]  * z + P[7];
    float cam2 = P[8] * x + P[9] * y + P[10] * z + P[11];
    float depth = cam2;
    float mx = cam0 / depth;
    float my = cam1 / depth;

    // quaternion -> rotation (normalize first, matching reference)
    float qw = rotations[n * 4 + 0];
    float qx = rotations[n * 4 + 1];
    float qy = rotations[n * 4 + 2];
    float qz = rotations[n * 4 + 3];
    float qn = sqrtf(qw * qw + qx * qx + qy * qy + qz * qz);
    qw /= qn; qx /= qn; qy /= qn; qz /= qn;
    float R00 = 1.f - 2.f * (qy * qy + qz * qz);
    float R01 = 2.f * (qx * qy - qw * qz);
    float R02 = 2.f * (qx * qz + qw * qy);
    float R10 = 2.f * (qx * qy + qw * qz);
    float R11 = 1.f - 2.f * (qx * qx + qz * qz);
    float R12 = 2.f * (qy * qz - qw * qx);
    float R20 = 2.f * (qx * qz - qw * qy);
    float R21 = 2.f * (qy * qz + qw * qx);
    float R22 = 1.f - 2.f * (qx * qx + qy * qy);

    float s0 = scales[n * 3 + 0];
    float s1 = scales[n * 3 + 1];
    float s2 = scales[n * 3 + 2];
    float v0 = s0 * s0, v1 = s1 * s1, v2 = s2 * s2;

    // cov3d = R diag(v) R^T (symmetric, keep 6 terms)
    float C00 = R00 * R00 * v0 + R01 * R01 * v1 + R02 * R02 * v2;
    float C01 = R00 * R10 * v0 + R01 * R11 * v1 + R02 * R12 * v2;
    float C02 = R00 * R20 * v0 + R01 * R21 * v1 + R02 * R22 * v2;
    float C11 = R10 * R10 * v0 + R11 * R11 * v1 + R12 * R12 * v2;
    float C12 = R10 * R20 * v0 + R11 * R21 * v1 + R12 * R22 * v2;
    float C22 = R20 * R20 * v0 + R21 * R21 * v1 + R22 * R22 * v2;

    // Jacobian uses WORLD z and world x,y (faithful to reference!)
    float fx = P[0];
    float fy = P[5];
    float iz = 1.0f / z;
    float a0 = fx * iz;
    float c0 = -fx * x * iz * iz;
    float b1 = fy * iz;
    float c1 = -fy * y * iz * iz;

    // cov2d = J C J^T, J0 = (a0, 0, c0), J1 = (0, b1, c1)
    float cov00 = a0 * a0 * C00 + 2.f * a0 * c0 * C02 + c0 * c0 * C22;
    float cov01 = a0 * b1 * C01 + a0 * c1 * C02 + c0 * b1 * C12 + c0 * c1 * C22;
    float cov11 = b1 * b1 * C11 + 2.f * b1 * c1 * C12 + c1 * c1 * C22;

    float det = cov00 * cov11 - cov01 * cov01;
    float invdet = 1.0f / det;
    float ia  = cov11 * invdet;       // inv[0][0]
    float ibc = -2.0f * cov01 * invdet; // inv[0][1] + inv[1][0]
    float id  = cov00 * invdet;       // inv[1][1]

    float4* p4 = (float4*)(params + (size_t)idx * 12);
    p4[0] = make_float4(mx, my, ia, ibc);
    p4[1] = make_float4(id, opacity[n], features[n * 3 + 0], features[n * 3 + 1]);
    p4[2] = make_float4(features[n * 3 + 2], 0.f, 0.f, 0.f);
    depths[idx] = depth;
}

// ---------------------------------------------------------------------------
// Kernel 2: O(N^2) stable rank sort (descending depth) + scatter params.
// rank(n) = #{ m : d_m > d_n  ||  (d_m == d_n && m < n) }
// ---------------------------------------------------------------------------
__global__ void gs_sort_scatter(const float* __restrict__ depths,
                                const float* __restrict__ params,
                                float* __restrict__ sorted,
                                int N)
{
    extern __shared__ float sdepth[];
    int b = blockIdx.y;
    int n = blockIdx.x * blockDim.x + threadIdx.x;
    const float* dep = depths + (size_t)b * N;
    for (int i = threadIdx.x; i < N; i += blockDim.x) sdepth[i] = dep[i];
    __syncthreads();
    if (n >= N) return;
    float dn = sdepth[n];
    int rank = 0;
    for (int m = 0; m < N; ++m) {
        float dm = sdepth[m];
        rank += (dm > dn) || (dm == dn && m < n) ? 1 : 0;
    }
    const float4* src = (const float4*)(params + ((size_t)b * N + n) * 12);
    float4* dst = (float4*)(sorted + ((size_t)b * N + rank) * 12);
    dst[0] = src[0];
    dst[1] = src[1];
    dst[2] = src[2];
}

// ---------------------------------------------------------------------------
// Kernel 3: rasterize one segment of the sorted gaussian list per block.
// Each block: 256 pixels x gaussians [g0, g1). Output per (seg, pixel):
// partial {r,g,b} (with local T starting at 1) and segment transmittance T.
// H, W are read from device scalars.
// ---------------------------------------------------------------------------
__global__ void gs_raster_partial(const float* __restrict__ sorted,
                                  float* __restrict__ partials,
                                  const int* __restrict__ pH,
                                  const int* __restrict__ pW,
                                  int N, int B, int HW, int nseg)
{
    extern __shared__ float4 sg4[];
    int H = *pH;
    int W = *pW;
    int pix = blockIdx.x * blockDim.x + threadIdx.x;   // index in B*HW
    int seg = blockIdx.y;
    int seglen = (N + nseg - 1) / nseg;
    int g0 = seg * seglen;
    int g1 = g0 + seglen; if (g1 > N) g1 = N;
    int cnt = g1 - g0;
    if (cnt < 0) cnt = 0;

    // all pixels in a block share the same batch b (HW multiple of 256 here)
    int b = (blockIdx.x * blockDim.x) / HW;

    // cooperative stage: cnt gaussians x 3 float4
    const float4* src = (const float4*)(sorted + ((size_t)b * N + g0) * 12);
    for (int i = threadIdx.x; i < cnt * 3; i += blockDim.x) sg4[i] = src[i];
    __syncthreads();

    if (pix >= B * HW) return;
    int pp = pix - b * HW;
    int h = pp / W;
    int w = pp - h * W;
    float px = 2.0f * (float)w / (float)(W - 1) - 1.0f;
    float py = 2.0f * (float)h / (float)(H - 1) - 1.0f;

    float T = 1.0f, cr = 0.f, cg = 0.f, cb = 0.f;
    #pragma unroll 4
    for (int g = 0; g < cnt; ++g) {
        float4 f0 = sg4[g * 3 + 0];   // mx, my, ia, ibc
        float4 f1 = sg4[g * 3 + 1];   // id, alpha, r, g
        float4 f2 = sg4[g * 3 + 2];   // b, pad...
        float dx = px - f0.x;
        float dy = py - f0.y;
        float maha = f0.z * dx * dx + f0.w * dx * dy + f1.x * dy * dy;
        float am = __expf(-0.5f * maha) * f1.y;
        float wgt = T * am;
        cr += wgt * f1.z;
        cg += wgt * f1.w;
        cb += wgt * f2.x;
        T -= T * am;                  // T *= (1 - am)
    }
    float* o = partials + ((size_t)seg * (size_t)(B * HW) + pix) * 4;
    o[0] = cr; o[1] = cg; o[2] = cb; o[3] = T;
}

// ---------------------------------------------------------------------------
// Kernel 4: chain the segments front(far)-to-back and write (B,3,H,W).
// ---------------------------------------------------------------------------
__global__ void gs_combine(const float* __restrict__ partials,
                           float* __restrict__ out,
                           int B, int HW, int nseg)
{
    int pix = blockIdx.x * blockDim.x + threadIdx.x;
    if (pix >= B * HW) return;
    int b = pix / HW;
    int pp = pix - b * HW;
    float T = 1.0f, cr = 0.f, cg = 0.f, cb = 0.f;
    for (int s = 0; s < nseg; ++s) {
        const float* p = partials + ((size_t)s * (size_t)(B * HW) + pix) * 4;
        cr += T * p[0];
        cg += T * p[1];
        cb += T * p[2];
        T *= p[3];
    }
    out[((size_t)b * 3 + 0) * HW + pp] = cr;
    out[((size_t)b * 3 + 1) * HW + pp] = cg;
    out[((size_t)b * 3 + 2) * HW + pp] = cb;
}

// ---------------------------------------------------------------------------
extern "C" void kernel_launch(void* const* d_in, const int* in_sizes, int n_in,
                              void* d_out, int out_size, void* d_ws, size_t ws_size,
                              hipStream_t stream)
{
    const float* pose      = (const float*)d_in[0];
    const float* positions = (const float*)d_in[1];
    const float* scales    = (const float*)d_in[2];
    const float* rotations = (const float*)d_in[3];
    const float* opacity   = (const float*)d_in[4];
    const float* features  = (const float*)d_in[5];
    const int*   pH        = (const int*)d_in[6];
    const int*   pW        = (const int*)d_in[7];

    int B = in_sizes[0] / 16;
    int N = in_sizes[1] / 3;
    int HW = out_size / (3 * B);

    float* out = (float*)d_out;

    // workspace layout
    float* depths = (float*)d_ws;                    // B*N
    float* params = depths + (size_t)B * N;          // B*N*12
    float* sorted = params + (size_t)B * N * 12;     // B*N*12
    float* partials = sorted + (size_t)B * N * 12;   // nseg*B*HW*4

    // choose nseg from available workspace (deterministic per call)
    size_t base_bytes = (size_t)B * N * 25 * sizeof(float);
    size_t avail = ws_size > base_bytes ? ws_size - base_bytes : 0;
    long long ns = (long long)(avail / ((size_t)B * HW * 4 * sizeof(float)));
    int nseg = (int)(ns > 16 ? 16 : ns);
    if (nseg < 1) nseg = 1;

    int bn = B * N;
    gs_preprocess<<<(bn + TPB - 1) / TPB, TPB, 0, stream>>>(
        pose, positions, scales, rotations, opacity, features,
        depths, params, N, B);

    dim3 g2((N + TPB - 1) / TPB, B);
    gs_sort_scatter<<<g2, TPB, N * sizeof(float), stream>>>(
        depths, params, sorted, N);

    int seglen = (N + nseg - 1) / nseg;
    dim3 g3((B * HW + TPB - 1) / TPB, nseg);
    gs_raster_partial<<<g3, TPB, (size_t)seglen * 3 * sizeof(float4), stream>>>(
        sorted, partials, pH, pW, N, B, HW, nseg);

    gs_combine<<<(B * HW + TPB - 1) / TPB, TPB, 0, stream>>>(
        partials, out, B, HW, nseg);
}

// Round 4
// 126.677 us; speedup vs baseline: 1.1734x; 1.1734x over previous
//
#include <hip/hip_runtime.h>
#include <math.h>

#define TPB 256
#define SORT_TPB 1024

// ---------------------------------------------------------------------------
// Order-preserving float->uint map (ascending uint == ascending float).
// ---------------------------------------------------------------------------
__device__ __forceinline__ unsigned int f2ord(float f) {
    unsigned int u = __float_as_uint(f);
    return (u & 0x80000000u) ? ~u : (u | 0x80000000u);
}

// ---------------------------------------------------------------------------
// Kernel 1: fused preprocess + bitonic sort + scatter. ONE block per batch.
// params layout per gaussian (stride 12 floats = 3 float4), pre-folded for
// the raster loop:
//   f4[0] = (mx, my, A, Bc)     A = -0.5*log2e*inv00, Bc = -0.5*log2e*(inv01+inv10)
//   f4[1] = (D, log2(alpha), r, g)   D = -0.5*log2e*inv11
//   f4[2] = (b, 0, 0, 0)
// raster computes  alpha_map = exp2( A*dx^2 + Bc*dx*dy + D*dy^2 + log2(alpha) )
// Sort key: u64 ( ~f2ord(depth) << 32 | idx )  -> ascending u64 sort is
// descending-depth, tie-broken by ascending idx == stable argsort(-depth).
// ---------------------------------------------------------------------------
__global__ __launch_bounds__(SORT_TPB) void gs_prep_sort(
    const float* __restrict__ pose,
    const float* __restrict__ positions,
    const float* __restrict__ scales,
    const float* __restrict__ rotations,
    const float* __restrict__ opacity,
    const float* __restrict__ features,
    float* __restrict__ params,   // scratch: B*N*12
    float* __restrict__ sorted,   // out:     B*N*12
    int N, int Npad)
{
    extern __shared__ unsigned long long keys[]; // Npad
    const int b = blockIdx.x;
    const int tid = threadIdx.x;
    const float* P = pose + b * 16;
    const float fx = P[0], fy = P[5];
    const float C_EXP = -0.72134752044448170f;   // -0.5 * log2(e)

    for (int n = tid; n < Npad; n += SORT_TPB) {
        if (n >= N) { keys[n] = 0xFFFFFFFFFFFFFFFFull; continue; }
        float x = positions[n * 3 + 0];
        float y = positions[n * 3 + 1];
        float z = positions[n * 3 + 2];

        float cam2 = P[8] * x + P[9] * y + P[10] * z + P[11];
        float depth = cam2;
        float inv_d = 1.0f / depth;
        float mx = (P[0] * x + P[1] * y + P[2] * z + P[3]) * inv_d;
        float my = (P[4] * x + P[5] * y + P[6] * z + P[7]) * inv_d;

        float qw = rotations[n * 4 + 0];
        float qx = rotations[n * 4 + 1];
        float qy = rotations[n * 4 + 2];
        float qz = rotations[n * 4 + 3];
        float qn = sqrtf(qw * qw + qx * qx + qy * qy + qz * qz);
        qw /= qn; qx /= qn; qy /= qn; qz /= qn;
        float R00 = 1.f - 2.f * (qy * qy + qz * qz);
        float R01 = 2.f * (qx * qy - qw * qz);
        float R02 = 2.f * (qx * qz + qw * qy);
        float R10 = 2.f * (qx * qy + qw * qz);
        float R11 = 1.f - 2.f * (qx * qx + qz * qz);
        float R12 = 2.f * (qy * qz - qw * qx);
        float R20 = 2.f * (qx * qz - qw * qy);
        float R21 = 2.f * (qy * qz + qw * qx);
        float R22 = 1.f - 2.f * (qx * qx + qy * qy);

        float s0 = scales[n * 3 + 0];
        float s1 = scales[n * 3 + 1];
        float s2 = scales[n * 3 + 2];
        float v0 = s0 * s0, v1 = s1 * s1, v2 = s2 * s2;

        float C00 = R00 * R00 * v0 + R01 * R01 * v1 + R02 * R02 * v2;
        float C01 = R00 * R10 * v0 + R01 * R11 * v1 + R02 * R12 * v2;
        float C02 = R00 * R20 * v0 + R01 * R21 * v1 + R02 * R22 * v2;
        float C11 = R10 * R10 * v0 + R11 * R11 * v1 + R12 * R12 * v2;
        float C12 = R10 * R20 * v0 + R11 * R21 * v1 + R12 * R22 * v2;
        float C22 = R20 * R20 * v0 + R21 * R21 * v1 + R22 * R22 * v2;

        // Jacobian uses WORLD z and world x,y (faithful to reference)
        float iz = 1.0f / z;
        float a0 = fx * iz;
        float c0 = -fx * x * iz * iz;
        float b1 = fy * iz;
        float c1 = -fy * y * iz * iz;

        float cov00 = a0 * a0 * C00 + 2.f * a0 * c0 * C02 + c0 * c0 * C22;
        float cov01 = a0 * b1 * C01 + a0 * c1 * C02 + c0 * b1 * C12 + c0 * c1 * C22;
        float cov11 = b1 * b1 * C11 + 2.f * b1 * c1 * C12 + c1 * c1 * C22;

        float det = cov00 * cov11 - cov01 * cov01;
        float invdet = 1.0f / det;
        float A  = C_EXP * cov11 * invdet;
        float Bc = C_EXP * -2.0f * cov01 * invdet;
        float D  = C_EXP * cov00 * invdet;
        float l2a = log2f(opacity[n]);

        float4* p4 = (float4*)(params + ((size_t)b * N + n) * 12);
        p4[0] = make_float4(mx, my, A, Bc);
        p4[1] = make_float4(D, l2a, features[n * 3 + 0], features[n * 3 + 1]);
        p4[2] = make_float4(features[n * 3 + 2], 0.f, 0.f, 0.f);

        unsigned int dk = ~f2ord(depth);
        keys[n] = ((unsigned long long)dk << 32) | (unsigned int)n;
    }
    __syncthreads();

    // bitonic sort (ascending) on Npad u64 keys
    for (int k = 2; k <= Npad; k <<= 1) {
        for (int j = k >> 1; j > 0; j >>= 1) {
            for (int i = tid; i < Npad; i += SORT_TPB) {
                int l = i ^ j;
                if (l > i) {
                    unsigned long long a = keys[i], c = keys[l];
                    bool asc = ((i & k) == 0);
                    if ((a > c) == asc) { keys[i] = c; keys[l] = a; }
                }
            }
            __syncthreads();
        }
    }

    // scatter params into sorted order
    for (int r = tid; r < N; r += SORT_TPB) {
        int idx = (int)(unsigned int)keys[r];
        const float4* src = (const float4*)(params + ((size_t)b * N + idx) * 12);
        float4* dst = (float4*)(sorted + ((size_t)b * N + r) * 12);
        dst[0] = src[0];
        dst[1] = src[1];
        dst[2] = src[2];
    }
}

// ---------------------------------------------------------------------------
// Kernel 2: rasterize one segment of the sorted list per block.
// ---------------------------------------------------------------------------
__global__ void gs_raster_partial(const float* __restrict__ sorted,
                                  float* __restrict__ partials,
                                  const int* __restrict__ pH,
                                  const int* __restrict__ pW,
                                  int N, int B, int HW, int nseg)
{
    extern __shared__ float4 sg4[];
    int H = *pH;
    int W = *pW;
    int pix = blockIdx.x * blockDim.x + threadIdx.x;   // index in B*HW
    int seg = blockIdx.y;
    int seglen = (N + nseg - 1) / nseg;
    int g0 = seg * seglen;
    int g1 = g0 + seglen; if (g1 > N) g1 = N;
    int cnt = g1 - g0;
    if (cnt < 0) cnt = 0;

    int b = (blockIdx.x * blockDim.x) / HW;   // HW % blockDim == 0 here

    const float4* src = (const float4*)(sorted + ((size_t)b * N + g0) * 12);
    for (int i = threadIdx.x; i < cnt * 3; i += blockDim.x) sg4[i] = src[i];
    __syncthreads();

    if (pix >= B * HW) return;
    int pp = pix - b * HW;
    int h = pp / W;
    int w = pp - h * W;
    float px = 2.0f * (float)w / (float)(W - 1) - 1.0f;
    float py = 2.0f * (float)h / (float)(H - 1) - 1.0f;

    float T = 1.0f, cr = 0.f, cg = 0.f, cb = 0.f;
    #pragma unroll 4
    for (int g = 0; g < cnt; ++g) {
        float4 f0 = sg4[g * 3 + 0];   // mx, my, A, Bc
        float4 f1 = sg4[g * 3 + 1];   // D, log2(alpha), r, g
        float4 f2 = sg4[g * 3 + 2];   // b, pad...
        float dx = px - f0.x;
        float dy = py - f0.y;
        float q = f1.y;
        q = fmaf(f1.x * dy, dy, q);
        q = fmaf(f0.w * dx, dy, q);
        q = fmaf(f0.z * dx, dx, q);
        float am = exp2f(q);
        float wgt = T * am;
        cr = fmaf(wgt, f1.z, cr);
        cg = fmaf(wgt, f1.w, cg);
        cb = fmaf(wgt, f2.x, cb);
        T = fmaf(-am, T, T);
    }
    float* o = partials + ((size_t)seg * (size_t)(B * HW) + pix) * 4;
    o[0] = cr; o[1] = cg; o[2] = cb; o[3] = T;
}

// ---------------------------------------------------------------------------
// Kernel 3: chain segments far-to-near and write (B,3,H,W).
// ---------------------------------------------------------------------------
__global__ void gs_combine(const float* __restrict__ partials,
                           float* __restrict__ out,
                           int B, int HW, int nseg)
{
    int pix = blockIdx.x * blockDim.x + threadIdx.x;
    if (pix >= B * HW) return;
    int b = pix / HW;
    int pp = pix - b * HW;
    float T = 1.0f, cr = 0.f, cg = 0.f, cb = 0.f;
    for (int s = 0; s < nseg; ++s) {
        const float* p = partials + ((size_t)s * (size_t)(B * HW) + pix) * 4;
        cr = fmaf(T, p[0], cr);
        cg = fmaf(T, p[1], cg);
        cb = fmaf(T, p[2], cb);
        T *= p[3];
    }
    out[((size_t)b * 3 + 0) * HW + pp] = cr;
    out[((size_t)b * 3 + 1) * HW + pp] = cg;
    out[((size_t)b * 3 + 2) * HW + pp] = cb;
}

// ---------------------------------------------------------------------------
extern "C" void kernel_launch(void* const* d_in, const int* in_sizes, int n_in,
                              void* d_out, int out_size, void* d_ws, size_t ws_size,
                              hipStream_t stream)
{
    const float* pose      = (const float*)d_in[0];
    const float* positions = (const float*)d_in[1];
    const float* scales    = (const float*)d_in[2];
    const float* rotations = (const float*)d_in[3];
    const float* opacity   = (const float*)d_in[4];
    const float* features  = (const float*)d_in[5];
    const int*   pH        = (const int*)d_in[6];
    const int*   pW        = (const int*)d_in[7];

    int B = in_sizes[0] / 16;
    int N = in_sizes[1] / 3;
    int HW = out_size / (3 * B);

    float* out = (float*)d_out;

    // workspace layout
    float* params   = (float*)d_ws;                   // B*N*12
    float* sorted   = params + (size_t)B * N * 12;    // B*N*12
    float* partials = sorted + (size_t)B * N * 12;    // nseg*B*HW*4

    // nseg from available workspace (deterministic per call)
    size_t base_bytes = (size_t)B * N * 24 * sizeof(float);
    size_t avail = ws_size > base_bytes ? ws_size - base_bytes : 0;
    long long ns = (long long)(avail / ((size_t)B * HW * 4 * sizeof(float)));
    int nseg = (int)(ns > 32 ? 32 : ns);
    if (nseg < 1) nseg = 1;

    int Npad = 1;
    while (Npad < N) Npad <<= 1;

    gs_prep_sort<<<B, SORT_TPB, Npad * sizeof(unsigned long long), stream>>>(
        pose, positions, scales, rotations, opacity, features,
        params, sorted, N, Npad);

    int seglen = (N + nseg - 1) / nseg;
    dim3 g3((B * HW + TPB - 1) / TPB, nseg);
    gs_raster_partial<<<g3, TPB, (size_t)seglen * 3 * sizeof(float4), stream>>>(
        sorted, partials, pH, pW, N, B, HW, nseg);

    gs_combine<<<(B * HW + TPB - 1) / TPB, TPB, 0, stream>>>(
        partials, out, B, HW, nseg);
}

// Round 5
// 124.274 us; speedup vs baseline: 1.1960x; 1.0193x over previous
//
#include <hip/hip_runtime.h>
#include <math.h>

#define TPB 256
#define PIXPT 4          // pixels per thread in raster
#define NSEG_MAX 64

// ---------------------------------------------------------------------------
// Order-preserving float->uint map (ascending uint == ascending float).
// ---------------------------------------------------------------------------
__device__ __forceinline__ unsigned int f2ord(float f) {
    unsigned int u = __float_as_uint(f);
    return (u & 0x80000000u) ? ~u : (u | 0x80000000u);
}

// ---------------------------------------------------------------------------
// Kernel 1: per-gaussian preprocess -> params (12 floats) + sort key (u64).
// params per gaussian, pre-folded for the raster loop:
//   f4[0] = (mx, my, A, Bc)     A  = -0.5*log2e*inv00, Bc = -0.5*log2e*(inv01+inv10)
//   f4[1] = (D, log2(alpha), r, g)   D = -0.5*log2e*inv11
//   f4[2] = (b, 0, 0, 0)
// raster computes alpha_map = exp2( A*dx^2 + Bc*dx*dy + D*dy^2 + log2(alpha) )
// key = ( ~f2ord(depth) << 32 ) | n  : ascending u64 == stable argsort(-depth)
// ---------------------------------------------------------------------------
__global__ void gs_preprocess(const float* __restrict__ pose,
                              const float* __restrict__ positions,
                              const float* __restrict__ scales,
                              const float* __restrict__ rotations,
                              const float* __restrict__ opacity,
                              const float* __restrict__ features,
                              float* __restrict__ params,
                              unsigned long long* __restrict__ keys,
                              int N, int B)
{
    int idx = blockIdx.x * blockDim.x + threadIdx.x;
    if (idx >= B * N) return;
    int b = idx / N;
    int n = idx - b * N;
    const float* P = pose + b * 16;
    const float C_EXP = -0.72134752044448170f;   // -0.5 * log2(e)

    float x = positions[n * 3 + 0];
    float y = positions[n * 3 + 1];
    float z = positions[n * 3 + 2];

    float depth = P[8] * x + P[9] * y + P[10] * z + P[11];
    float inv_d = 1.0f / depth;
    float mx = (P[0] * x + P[1] * y + P[2] * z + P[3]) * inv_d;
    float my = (P[4] * x + P[5] * y + P[6] * z + P[7]) * inv_d;

    float qw = rotations[n * 4 + 0];
    float qx = rotations[n * 4 + 1];
    float qy = rotations[n * 4 + 2];
    float qz = rotations[n * 4 + 3];
    float qn = sqrtf(qw * qw + qx * qx + qy * qy + qz * qz);
    qw /= qn; qx /= qn; qy /= qn; qz /= qn;
    float R00 = 1.f - 2.f * (qy * qy + qz * qz);
    float R01 = 2.f * (qx * qy - qw * qz);
    float R02 = 2.f * (qx * qz + qw * qy);
    float R10 = 2.f * (qx * qy + qw * qz);
    float R11 = 1.f - 2.f * (qx * qx + qz * qz);
    float R12 = 2.f * (qy * qz - qw * qx);
    float R20 = 2.f * (qx * qz - qw * qy);
    float R21 = 2.f * (qy * qz + qw * qx);
    float R22 = 1.f - 2.f * (qx * qx + qy * qy);

    float s0 = scales[n * 3 + 0];
    float s1 = scales[n * 3 + 1];
    float s2 = scales[n * 3 + 2];
    float v0 = s0 * s0, v1 = s1 * s1, v2 = s2 * s2;

    float C00 = R00 * R00 * v0 + R01 * R01 * v1 + R02 * R02 * v2;
    float C01 = R00 * R10 * v0 + R01 * R11 * v1 + R02 * R12 * v2;
    float C02 = R00 * R20 * v0 + R01 * R21 * v1 + R02 * R22 * v2;
    float C11 = R10 * R10 * v0 + R11 * R11 * v1 + R12 * R12 * v2;
    float C12 = R10 * R20 * v0 + R11 * R21 * v1 + R12 * R22 * v2;
    float C22 = R20 * R20 * v0 + R21 * R21 * v1 + R22 * R22 * v2;

    // Jacobian uses WORLD z and world x,y (faithful to reference)
    float fx = P[0], fy = P[5];
    float iz = 1.0f / z;
    float a0 = fx * iz;
    float c0 = -fx * x * iz * iz;
    float b1 = fy * iz;
    float c1 = -fy * y * iz * iz;

    float cov00 = a0 * a0 * C00 + 2.f * a0 * c0 * C02 + c0 * c0 * C22;
    float cov01 = a0 * b1 * C01 + a0 * c1 * C02 + c0 * b1 * C12 + c0 * c1 * C22;
    float cov11 = b1 * b1 * C11 + 2.f * b1 * c1 * C12 + c1 * c1 * C22;

    float det = cov00 * cov11 - cov01 * cov01;
    float invdet = 1.0f / det;
    float A  = C_EXP * cov11 * invdet;
    float Bc = C_EXP * -2.0f * cov01 * invdet;
    float D  = C_EXP * cov00 * invdet;
    float l2a = log2f(opacity[n]);

    float4* p4 = (float4*)(params + (size_t)idx * 12);
    p4[0] = make_float4(mx, my, A, Bc);
    p4[1] = make_float4(D, l2a, features[n * 3 + 0], features[n * 3 + 1]);
    p4[2] = make_float4(features[n * 3 + 2], 0.f, 0.f, 0.f);

    keys[idx] = ((unsigned long long)(~f2ord(depth)) << 32) | (unsigned int)n;
}

// ---------------------------------------------------------------------------
// Kernel 2: parallel rank -> order.  8 scanner-lanes per gaussian.
// rank(n) = #{ m : key[m] < key[n] }   (keys unique) ; order[rank] = n.
// Block: 256 threads = 32 gaussians x 8 scanners. Grid: ceil(N/32) per batch.
// ---------------------------------------------------------------------------
__global__ void gs_rank(const unsigned long long* __restrict__ keys,
                        int* __restrict__ order,
                        int N)
{
    extern __shared__ unsigned long long skey[];   // N keys
    int b = blockIdx.y;
    const unsigned long long* kb = keys + (size_t)b * N;
    for (int i = threadIdx.x; i < N; i += blockDim.x) skey[i] = kb[i];
    __syncthreads();

    int g = blockIdx.x * 32 + (threadIdx.x >> 3);  // gaussian index
    int s = threadIdx.x & 7;                       // scanner lane
    if (g >= N) return;
    unsigned long long kn = skey[g];
    int chunk = (N + 7) >> 3;
    int m0 = s * chunk;
    int m1 = m0 + chunk; if (m1 > N) m1 = N;
    int cnt = 0;
    #pragma unroll 4
    for (int m = m0; m < m1; ++m) cnt += (skey[m] < kn) ? 1 : 0;
    cnt += __shfl_down(cnt, 4, 8);
    cnt += __shfl_down(cnt, 2, 8);
    cnt += __shfl_down(cnt, 1, 8);
    if (s == 0) order[(size_t)b * N + cnt] = g;
}

// ---------------------------------------------------------------------------
// Kernel 3: rasterize one segment per block, PIXPT pixels per thread.
// Stages the segment's gaussians into LDS via order[] indirection.
// ---------------------------------------------------------------------------
__global__ void gs_raster_partial(const float* __restrict__ params,
                                  const int* __restrict__ order,
                                  float* __restrict__ partials,
                                  const int* __restrict__ pH,
                                  const int* __restrict__ pW,
                                  int N, int B, int HW, int nseg)
{
    extern __shared__ float4 sg4[];
    int H = *pH;
    int W = *pW;
    int seg = blockIdx.y;
    int seglen = (N + nseg - 1) / nseg;
    int g0 = seg * seglen;
    int g1 = g0 + seglen; if (g1 > N) g1 = N;
    int cnt = g1 - g0; if (cnt < 0) cnt = 0;

    int pixbase = blockIdx.x * (TPB * PIXPT);
    int b = pixbase / HW;   // requires block pixel-span within one batch (HW % (TPB*PIXPT) == 0 here)

    // stage cnt gaussians x 3 float4 via indirection
    const int* ob = order + (size_t)b * N + g0;
    for (int i = threadIdx.x; i < cnt * 3; i += TPB) {
        int gi = i / 3;
        int r  = i - gi * 3;
        int idx = ob[gi];
        sg4[i] = ((const float4*)(params + ((size_t)b * N + idx) * 12))[r];
    }
    __syncthreads();

    float px[PIXPT], py[PIXPT];
    float T[PIXPT], cr[PIXPT], cg[PIXPT], cb[PIXPT];
    bool valid[PIXPT];
    #pragma unroll
    for (int k = 0; k < PIXPT; ++k) {
        int pix = pixbase + threadIdx.x + k * TPB;
        valid[k] = (pix < B * HW);
        int pp = valid[k] ? (pix - b * HW) : 0;
        int h = pp / W;
        int w = pp - h * W;
        px[k] = 2.0f * (float)w / (float)(W - 1) - 1.0f;
        py[k] = 2.0f * (float)h / (float)(H - 1) - 1.0f;
        T[k] = 1.0f; cr[k] = 0.f; cg[k] = 0.f; cb[k] = 0.f;
    }

    for (int g = 0; g < cnt; ++g) {
        float4 f0 = sg4[g * 3 + 0];   // mx, my, A, Bc
        float4 f1 = sg4[g * 3 + 1];   // D, log2(alpha), r, g
        float4 f2 = sg4[g * 3 + 2];   // b, pad...
        #pragma unroll
        for (int k = 0; k < PIXPT; ++k) {
            float dx = px[k] - f0.x;
            float dy = py[k] - f0.y;
            float q = f1.y;
            q = fmaf(f1.x * dy, dy, q);
            q = fmaf(f0.w * dx, dy, q);
            q = fmaf(f0.z * dx, dx, q);
            float am = exp2f(q);
            float wgt = T[k] * am;
            cr[k] = fmaf(wgt, f1.z, cr[k]);
            cg[k] = fmaf(wgt, f1.w, cg[k]);
            cb[k] = fmaf(wgt, f2.x, cb[k]);
            T[k] = fmaf(-am, T[k], T[k]);
        }
    }

    #pragma unroll
    for (int k = 0; k < PIXPT; ++k) {
        int pix = pixbase + threadIdx.x + k * TPB;
        if (!valid[k]) continue;
        float4* o = (float4*)(partials + ((size_t)seg * (size_t)(B * HW) + pix) * 4);
        *o = make_float4(cr[k], cg[k], cb[k], T[k]);
    }
}

// ---------------------------------------------------------------------------
// Kernel 4: chain segments far-to-near and write (B,3,H,W).
// ---------------------------------------------------------------------------
__global__ void gs_combine(const float* __restrict__ partials,
                           float* __restrict__ out,
                           int B, int HW, int nseg)
{
    int pix = blockIdx.x * blockDim.x + threadIdx.x;
    if (pix >= B * HW) return;
    int b = pix / HW;
    int pp = pix - b * HW;
    float T = 1.0f, cr = 0.f, cg = 0.f, cb = 0.f;
    for (int s = 0; s < nseg; ++s) {
        float4 p = *(const float4*)(partials + ((size_t)s * (size_t)(B * HW) + pix) * 4);
        cr = fmaf(T, p.x, cr);
        cg = fmaf(T, p.y, cg);
        cb = fmaf(T, p.z, cb);
        T *= p.w;
    }
    out[((size_t)b * 3 + 0) * HW + pp] = cr;
    out[((size_t)b * 3 + 1) * HW + pp] = cg;
    out[((size_t)b * 3 + 2) * HW + pp] = cb;
}

// ---------------------------------------------------------------------------
extern "C" void kernel_launch(void* const* d_in, const int* in_sizes, int n_in,
                              void* d_out, int out_size, void* d_ws, size_t ws_size,
                              hipStream_t stream)
{
    const float* pose      = (const float*)d_in[0];
    const float* positions = (const float*)d_in[1];
    const float* scales    = (const float*)d_in[2];
    const float* rotations = (const float*)d_in[3];
    const float* opacity   = (const float*)d_in[4];
    const float* features  = (const float*)d_in[5];
    const int*   pH        = (const int*)d_in[6];
    const int*   pW        = (const int*)d_in[7];

    int B = in_sizes[0] / 16;
    int N = in_sizes[1] / 3;
    int HW = out_size / (3 * B);

    float* out = (float*)d_out;

    // workspace layout (16-byte aligned chunks)
    char* wp = (char*)d_ws;
    float* params = (float*)wp;
    wp += ((size_t)B * N * 12 * sizeof(float) + 15) & ~(size_t)15;
    unsigned long long* keys = (unsigned long long*)wp;
    wp += ((size_t)B * N * sizeof(unsigned long long) + 15) & ~(size_t)15;
    int* order = (int*)wp;
    wp += ((size_t)B * N * sizeof(int) + 15) & ~(size_t)15;
    float* partials = (float*)wp;

    size_t used = (size_t)(wp - (char*)d_ws);
    size_t avail = ws_size > used ? ws_size - used : 0;
    long long ns = (long long)(avail / ((size_t)B * HW * 4 * sizeof(float)));
    int nseg = (int)(ns > NSEG_MAX ? NSEG_MAX : ns);
    if (nseg < 1) nseg = 1;

    int bn = B * N;
    gs_preprocess<<<(bn + TPB - 1) / TPB, TPB, 0, stream>>>(
        pose, positions, scales, rotations, opacity, features,
        params, keys, N, B);

    dim3 g2((N + 31) / 32, B);
    gs_rank<<<g2, TPB, N * sizeof(unsigned long long), stream>>>(keys, order, N);

    int seglen = (N + nseg - 1) / nseg;
    dim3 g3((B * HW + TPB * PIXPT - 1) / (TPB * PIXPT), nseg);
    gs_raster_partial<<<g3, TPB, (size_t)seglen * 3 * sizeof(float4), stream>>>(
        params, order, partials, pH, pW, N, B, HW, nseg);

    gs_combine<<<(B * HW + TPB - 1) / TPB, TPB, 0, stream>>>(
        partials, out, B, HW, nseg);
}

// Round 6
// 120.854 us; speedup vs baseline: 1.2299x; 1.0283x over previous
//
#include <hip/hip_runtime.h>
#include <math.h>

#define TPB 256
#define PIXPT 4          // pixels per thread in raster
#define NSEG_MAX 64

// ---------------------------------------------------------------------------
// Order-preserving float->uint map (ascending uint == ascending float).
// ---------------------------------------------------------------------------
__device__ __forceinline__ unsigned int f2ord(float f) {
    unsigned int u = __float_as_uint(f);
    return (u & 0x80000000u) ? ~u : (u | 0x80000000u);
}

// ---------------------------------------------------------------------------
// Kernel 1: fused preprocess + parallel rank, writing params directly to the
// depth-sorted slot.  Grid: (ceil(N/32), B), 256 threads.
//
// Phase 1: all threads cooperatively compute all N sort keys into LDS
//          (key = ~f2ord(depth) << 32 | n  -> ascending u64 == stable
//           argsort(-depth); depth = row2 of pose applied to position).
// Phase 2: 8 scanner lanes per gaussian count keys < own key. Interleaved
//          scan m = s + 8*i  -> 8 distinct LDS addresses per wave, 64 B
//          apart -> banks {2s, 2s+1}: conflict-free, broadcast across groups.
// Phase 3: lane s==0 runs the full per-gaussian preprocess and writes the
//          12-float param block to sorted[rank].
//
// params per gaussian (pre-folded for the raster loop):
//   f4[0] = (mx, my, A, Bc)   A = -0.5*log2e*inv00, Bc = -0.5*log2e*(inv01+inv10)
//   f4[1] = (D, log2(alpha), r, g)   D = -0.5*log2e*inv11
//   f4[2] = (b, 0, 0, 0)
// raster computes alpha_map = exp2( A*dx^2 + Bc*dx*dy + D*dy^2 + log2(alpha) )
// ---------------------------------------------------------------------------
__global__ void gs_prep_rank(const float* __restrict__ pose,
                             const float* __restrict__ positions,
                             const float* __restrict__ scales,
                             const float* __restrict__ rotations,
                             const float* __restrict__ opacity,
                             const float* __restrict__ features,
                             float* __restrict__ sorted,   // B*N*12
                             int N)
{
    extern __shared__ unsigned long long skey[];   // N keys
    const int b = blockIdx.y;
    const float* P = pose + b * 16;
    const float C_EXP = -0.72134752044448170f;     // -0.5 * log2(e)

    // phase 1: keys
    for (int n = threadIdx.x; n < N; n += TPB) {
        float x = positions[n * 3 + 0];
        float y = positions[n * 3 + 1];
        float z = positions[n * 3 + 2];
        float depth = P[8] * x + P[9] * y + P[10] * z + P[11];
        skey[n] = ((unsigned long long)(~f2ord(depth)) << 32) | (unsigned int)n;
    }
    __syncthreads();

    // phase 2: rank
    int g = blockIdx.x * 32 + (threadIdx.x >> 3);
    int s = threadIdx.x & 7;
    if (g >= N) return;
    unsigned long long kn = skey[g];
    int cnt = 0;
    for (int m = s; m < N; m += 8) cnt += (skey[m] < kn) ? 1 : 0;
    cnt += __shfl_down(cnt, 4, 8);
    cnt += __shfl_down(cnt, 2, 8);
    cnt += __shfl_down(cnt, 1, 8);
    if (s != 0) return;
    int rank = cnt;

    // phase 3: preprocess gaussian g -> sorted[rank]
    float x = positions[g * 3 + 0];
    float y = positions[g * 3 + 1];
    float z = positions[g * 3 + 2];

    float depth = P[8] * x + P[9] * y + P[10] * z + P[11];
    float inv_d = 1.0f / depth;
    float mx = (P[0] * x + P[1] * y + P[2] * z + P[3]) * inv_d;
    float my = (P[4] * x + P[5] * y + P[6] * z + P[7]) * inv_d;

    float qw = rotations[g * 4 + 0];
    float qx = rotations[g * 4 + 1];
    float qy = rotations[g * 4 + 2];
    float qz = rotations[g * 4 + 3];
    float qn = sqrtf(qw * qw + qx * qx + qy * qy + qz * qz);
    qw /= qn; qx /= qn; qy /= qn; qz /= qn;
    float R00 = 1.f - 2.f * (qy * qy + qz * qz);
    float R01 = 2.f * (qx * qy - qw * qz);
    float R02 = 2.f * (qx * qz + qw * qy);
    float R10 = 2.f * (qx * qy + qw * qz);
    float R11 = 1.f - 2.f * (qx * qx + qz * qz);
    float R12 = 2.f * (qy * qz - qw * qx);
    float R20 = 2.f * (qx * qz - qw * qy);
    float R21 = 2.f * (qy * qz + qw * qx);
    float R22 = 1.f - 2.f * (qx * qx + qy * qy);

    float s0 = scales[g * 3 + 0];
    float s1 = scales[g * 3 + 1];
    float s2 = scales[g * 3 + 2];
    float v0 = s0 * s0, v1 = s1 * s1, v2 = s2 * s2;

    float C00 = R00 * R00 * v0 + R01 * R01 * v1 + R02 * R02 * v2;
    float C01 = R00 * R10 * v0 + R01 * R11 * v1 + R02 * R12 * v2;
    float C02 = R00 * R20 * v0 + R01 * R21 * v1 + R02 * R22 * v2;
    float C11 = R10 * R10 * v0 + R11 * R11 * v1 + R12 * R12 * v2;
    float C12 = R10 * R20 * v0 + R11 * R21 * v1 + R12 * R22 * v2;
    float C22 = R20 * R20 * v0 + R21 * R21 * v1 + R22 * R22 * v2;

    // Jacobian uses WORLD z and world x,y (faithful to reference)
    float fx = P[0], fy = P[5];
    float iz = 1.0f / z;
    float a0 = fx * iz;
    float c0 = -fx * x * iz * iz;
    float b1 = fy * iz;
    float c1 = -fy * y * iz * iz;

    float cov00 = a0 * a0 * C00 + 2.f * a0 * c0 * C02 + c0 * c0 * C22;
    float cov01 = a0 * b1 * C01 + a0 * c1 * C02 + c0 * b1 * C12 + c0 * c1 * C22;
    float cov11 = b1 * b1 * C11 + 2.f * b1 * c1 * C12 + c1 * c1 * C22;

    float det = cov00 * cov11 - cov01 * cov01;
    float invdet = 1.0f / det;
    float A  = C_EXP * cov11 * invdet;
    float Bc = C_EXP * -2.0f * cov01 * invdet;
    float D  = C_EXP * cov00 * invdet;
    float l2a = log2f(opacity[g]);

    float4* p4 = (float4*)(sorted + ((size_t)b * N + rank) * 12);
    p4[0] = make_float4(mx, my, A, Bc);
    p4[1] = make_float4(D, l2a, features[g * 3 + 0], features[g * 3 + 1]);
    p4[2] = make_float4(features[g * 3 + 2], 0.f, 0.f, 0.f);
}

// ---------------------------------------------------------------------------
// Kernel 2: rasterize one segment per block, PIXPT pixels per thread.
// Coalesced LDS staging from the already-sorted param array.
// ---------------------------------------------------------------------------
__global__ void gs_raster_partial(const float* __restrict__ sorted,
                                  float* __restrict__ partials,
                                  const int* __restrict__ pH,
                                  const int* __restrict__ pW,
                                  int N, int B, int HW, int nseg)
{
    extern __shared__ float4 sg4[];
    int H = *pH;
    int W = *pW;
    int seg = blockIdx.y;
    int seglen = (N + nseg - 1) / nseg;
    int g0 = seg * seglen;
    int g1 = g0 + seglen; if (g1 > N) g1 = N;
    int cnt = g1 - g0; if (cnt < 0) cnt = 0;

    int pixbase = blockIdx.x * (TPB * PIXPT);
    int b = pixbase / HW;   // block pixel-span stays within one batch here

    const float4* src = (const float4*)(sorted + ((size_t)b * N + g0) * 12);
    for (int i = threadIdx.x; i < cnt * 3; i += TPB) sg4[i] = src[i];
    __syncthreads();

    float px[PIXPT], py[PIXPT];
    float T[PIXPT], cr[PIXPT], cg[PIXPT], cb[PIXPT];
    bool valid[PIXPT];
    #pragma unroll
    for (int k = 0; k < PIXPT; ++k) {
        int pix = pixbase + threadIdx.x + k * TPB;
        valid[k] = (pix < B * HW);
        int pp = valid[k] ? (pix - b * HW) : 0;
        int h = pp / W;
        int w = pp - h * W;
        px[k] = 2.0f * (float)w / (float)(W - 1) - 1.0f;
        py[k] = 2.0f * (float)h / (float)(H - 1) - 1.0f;
        T[k] = 1.0f; cr[k] = 0.f; cg[k] = 0.f; cb[k] = 0.f;
    }

    for (int g = 0; g < cnt; ++g) {
        float4 f0 = sg4[g * 3 + 0];   // mx, my, A, Bc
        float4 f1 = sg4[g * 3 + 1];   // D, log2(alpha), r, g
        float4 f2 = sg4[g * 3 + 2];   // b, pad...
        #pragma unroll
        for (int k = 0; k < PIXPT; ++k) {
            float dx = px[k] - f0.x;
            float dy = py[k] - f0.y;
            float q = f1.y;
            q = fmaf(f1.x * dy, dy, q);
            q = fmaf(f0.w * dx, dy, q);
            q = fmaf(f0.z * dx, dx, q);
            float am = exp2f(q);
            float wgt = T[k] * am;
            cr[k] = fmaf(wgt, f1.z, cr[k]);
            cg[k] = fmaf(wgt, f1.w, cg[k]);
            cb[k] = fmaf(wgt, f2.x, cb[k]);
            T[k] = fmaf(-am, T[k], T[k]);
        }
    }

    #pragma unroll
    for (int k = 0; k < PIXPT; ++k) {
        int pix = pixbase + threadIdx.x + k * TPB;
        if (!valid[k]) continue;
        float4* o = (float4*)(partials + ((size_t)seg * (size_t)(B * HW) + pix) * 4);
        *o = make_float4(cr[k], cg[k], cb[k], T[k]);
    }
}

// ---------------------------------------------------------------------------
// Kernel 3: chain segments far-to-near and write (B,3,H,W).
// ---------------------------------------------------------------------------
__global__ void gs_combine(const float* __restrict__ partials,
                           float* __restrict__ out,
                           int B, int HW, int nseg)
{
    int pix = blockIdx.x * blockDim.x + threadIdx.x;
    if (pix >= B * HW) return;
    int b = pix / HW;
    int pp = pix - b * HW;
    float T = 1.0f, cr = 0.f, cg = 0.f, cb = 0.f;
    for (int s = 0; s < nseg; ++s) {
        float4 p = *(const float4*)(partials + ((size_t)s * (size_t)(B * HW) + pix) * 4);
        cr = fmaf(T, p.x, cr);
        cg = fmaf(T, p.y, cg);
        cb = fmaf(T, p.z, cb);
        T *= p.w;
    }
    out[((size_t)b * 3 + 0) * HW + pp] = cr;
    out[((size_t)b * 3 + 1) * HW + pp] = cg;
    out[((size_t)b * 3 + 2) * HW + pp] = cb;
}

// ---------------------------------------------------------------------------
extern "C" void kernel_launch(void* const* d_in, const int* in_sizes, int n_in,
                              void* d_out, int out_size, void* d_ws, size_t ws_size,
                              hipStream_t stream)
{
    const float* pose      = (const float*)d_in[0];
    const float* positions = (const float*)d_in[1];
    const float* scales    = (const float*)d_in[2];
    const float* rotations = (const float*)d_in[3];
    const float* opacity   = (const float*)d_in[4];
    const float* features  = (const float*)d_in[5];
    const int*   pH        = (const int*)d_in[6];
    const int*   pW        = (const int*)d_in[7];

    int B = in_sizes[0] / 16;
    int N = in_sizes[1] / 3;
    int HW = out_size / (3 * B);

    float* out = (float*)d_out;

    // workspace layout (16-byte aligned chunks)
    char* wp = (char*)d_ws;
    float* sorted = (float*)wp;
    wp += ((size_t)B * N * 12 * sizeof(float) + 15) & ~(size_t)15;
    float* partials = (float*)wp;

    size_t used = (size_t)(wp - (char*)d_ws);
    size_t avail = ws_size > used ? ws_size - used : 0;
    long long ns = (long long)(avail / ((size_t)B * HW * 4 * sizeof(float)));
    int nseg = (int)(ns > NSEG_MAX ? NSEG_MAX : ns);
    if (nseg < 1) nseg = 1;

    dim3 g1((N + 31) / 32, B);
    gs_prep_rank<<<g1, TPB, N * sizeof(unsigned long long), stream>>>(
        pose, positions, scales, rotations, opacity, features, sorted, N);

    int seglen = (N + nseg - 1) / nseg;
    dim3 g3((B * HW + TPB * PIXPT - 1) / (TPB * PIXPT), nseg);
    gs_raster_partial<<<g3, TPB, (size_t)seglen * 3 * sizeof(float4), stream>>>(
        sorted, partials, pH, pW, N, B, HW, nseg);

    gs_combine<<<(B * HW + TPB - 1) / TPB, TPB, 0, stream>>>(
        partials, out, B, HW, nseg);
}